// Round 6
// baseline (301.230 us; speedup 1.0000x reference)
//
#include <hip/hip_runtime.h>

// Problem constants
#define B_   2
#define S_   2048
#define D_   2048
#define NQ_  32
#define NKV_ 8
#define HD_  64
// g = NQ/NKV = 4

#define QSCALE 0.18033688011112042f   // log2(e)/sqrt(HD), folded into Wq at convert

typedef unsigned short u16;
typedef __bf16 bf16x8 __attribute__((ext_vector_type(8)));
typedef short  s16x4  __attribute__((ext_vector_type(4)));
typedef float  f32x4  __attribute__((ext_vector_type(4)));

#define GLB __attribute__((address_space(1)))
#define LDS __attribute__((address_space(3)))

__device__ inline u16 f2b(float f){
  union { float f; unsigned u; } v; v.f = f;
  unsigned r = (v.u + 0x7fffu + ((v.u >> 16) & 1u)) >> 16;
  return (u16)r;
}
__device__ inline float b2f(u16 b){
  union { unsigned u; float f; } v; v.u = ((unsigned)b) << 16;
  return v.f;
}

__device__ inline f32x4 mfma32(bf16x8 a, bf16x8 b, f32x4 c){
  return __builtin_amdgcn_mfma_f32_16x16x32_bf16(a, b, c, 0, 0, 0);
}

// concat two s16x4 (bf16 bit patterns) into one bf16x8 MFMA operand
__device__ inline bf16x8 cat8(s16x4 lo, s16x4 hi){
  union { struct { s16x4 a, b; } s; bf16x8 v; } u;
  u.s.a = lo; u.s.b = hi; return u.v;
}

// exp2 of 4 scores -> RNE-packed bf16 via v_cvt_pk_bf16_f32
__device__ inline s16x4 exppack(f32x4 z){
  float p0 = __builtin_amdgcn_exp2f(z[0]);
  float p1 = __builtin_amdgcn_exp2f(z[1]);
  float p2 = __builtin_amdgcn_exp2f(z[2]);
  float p3 = __builtin_amdgcn_exp2f(z[3]);
  union { uint2 u; s16x4 v; } r;
  asm("v_cvt_pk_bf16_f32 %0, %1, %2" : "=v"(r.u.x) : "v"(p0), "v"(p1));
  asm("v_cvt_pk_bf16_f32 %0, %1, %2" : "=v"(r.u.y) : "v"(p2), "v"(p3));
  return r.v;
}

// ---------- fp32 -> bf16 convert (all 5 regions) + RoPE cos/sin table -------
__global__ void k_f2b_all(const float* __restrict__ x,  const float* __restrict__ wq,
                          const float* __restrict__ wk, const float* __restrict__ wv,
                          const float* __restrict__ wo,
                          u16* __restrict__ xb, u16* __restrict__ wqkvb, u16* __restrict__ wob,
                          float* __restrict__ tab){
  int i = blockIdx.x * blockDim.x + threadIdx.x;   // < 4718592 + 16384
  if (i < 4718592){
    const float* src; u16* dst; int off; float sc = 1.0f;
    if (i < 2097152)      { src = x;  dst = xb;                  off = i; }
    else if (i < 3145728) { src = wq; dst = wqkvb;               off = i - 2097152; sc = QSCALE; }
    else if (i < 3407872) { src = wk; dst = wqkvb + 2048*2048;   off = i - 3145728; }
    else if (i < 3670016) { src = wv; dst = wqkvb + 2560*2048;   off = i - 3407872; }
    else                  { src = wo; dst = wob;                 off = i - 3670016; }
    float4 f = ((const float4*)src)[off];
    uint2 pk;
    pk.x = (unsigned)f2b(f.x*sc) | ((unsigned)f2b(f.y*sc) << 16);
    pk.y = (unsigned)f2b(f.z*sc) | ((unsigned)f2b(f.w*sc) << 16);
    ((uint2*)dst)[off] = pk;
  } else {
    int t = i - 4718592;                // < 16384 : 4 table entries per thread
    float fs = (float)(t >> 3);         // s
    int d2b  = (t & 7) * 4;             // d2 base
    float a0 = fs * __expf(-(float)(d2b    ) * (9.210340371976184f/32.0f));
    float a1 = fs * __expf(-(float)(d2b + 1) * (9.210340371976184f/32.0f));
    float a2 = fs * __expf(-(float)(d2b + 2) * (9.210340371976184f/32.0f));
    float a3 = fs * __expf(-(float)(d2b + 3) * (9.210340371976184f/32.0f));
    float4 o0, o1;
    o0.x = __cosf(a0); o0.y = __sinf(a0); o0.z = __cosf(a1); o0.w = __sinf(a1);
    o1.x = __cosf(a2); o1.y = __sinf(a2); o1.z = __cosf(a3); o1.w = __sinf(a3);
    ((float4*)tab)[2*t]   = o0;
    ((float4*)tab)[2*t+1] = o1;
  }
}

// ======================= shared GEMM core (BK=64, swizzled) =================
#define GEMM_CORE(K)                                                           \
  __shared__ __align__(16) u16 As[128*64];                                     \
  __shared__ __align__(16) u16 Bs[128*64];                                     \
  const int tid  = threadIdx.x;                                               \
  const int lane = tid & 63;                                                  \
  const int wave = tid >> 6;                                                  \
  const int wm = wave >> 1, wn = wave & 1;                                    \
  const int quad = lane >> 4, l16 = lane & 15;                                \
  const u16* Ab = A  + (size_t)blockIdx.y * 128 * (K);                        \
  const u16* Bb = Bm + (size_t)blockIdx.x * 128 * (K);                        \
  f32x4 acc[4][4];                                                            \
  for (int i = 0; i < 4; i++)                                                 \
    for (int j = 0; j < 4; j++) acc[i][j] = (f32x4){0.f, 0.f, 0.f, 0.f};      \
  const int R0 = wave * 32;                                                   \
  const int lr = lane >> 3;                                                   \
  const int gc = ((lane & 7) ^ lr) * 8;                                       \
  const int sk = l16 & 7;                                                     \
  for (int k0 = 0; k0 < (K); k0 += 64){                                       \
    __syncthreads();                                                          \
    _Pragma("unroll")                                                         \
    for (int m = 0; m < 4; m++){                                              \
      const u16* ga = Ab + (size_t)(R0 + m*8 + lr) * (K) + k0 + gc;           \
      const u16* gb = Bb + (size_t)(R0 + m*8 + lr) * (K) + k0 + gc;           \
      __builtin_amdgcn_global_load_lds((const GLB void*)ga, (LDS void*)&As[(R0 + m*8)*64], 16, 0, 0); \
      __builtin_amdgcn_global_load_lds((const GLB void*)gb, (LDS void*)&Bs[(R0 + m*8)*64], 16, 0, 0); \
    }                                                                          \
    __syncthreads();                                                          \
    bf16x8 af[4][2], bfr[4][2];                                               \
    _Pragma("unroll")                                                         \
    for (int i = 0; i < 4; i++)                                               \
      _Pragma("unroll")                                                       \
      for (int h = 0; h < 2; h++)                                             \
        af[i][h]  = *(const bf16x8*)&As[(wm*64 + i*16 + l16)*64 + (((h*4 + quad) ^ sk)*8)]; \
    _Pragma("unroll")                                                         \
    for (int j = 0; j < 4; j++)                                               \
      _Pragma("unroll")                                                       \
      for (int h = 0; h < 2; h++)                                             \
        bfr[j][h] = *(const bf16x8*)&Bs[(wn*64 + j*16 + l16)*64 + (((h*4 + quad) ^ sk)*8)]; \
    _Pragma("unroll")                                                         \
    for (int i = 0; i < 4; i++)                                               \
      _Pragma("unroll")                                                       \
      for (int j = 0; j < 4; j++){                                            \
        acc[i][j] = __builtin_amdgcn_mfma_f32_16x16x32_bf16(af[i][0], bfr[j][0], acc[i][j], 0, 0, 0); \
        acc[i][j] = __builtin_amdgcn_mfma_f32_16x16x32_bf16(af[i][1], bfr[j][1], acc[i][j], 0, 0, 0); \
      }                                                                        \
  }

// ---------------- fused QKV GEMM + RoPE + scatter ----------------
// qT/kT use a PERMUTED head-dim layout: d' = 4*(d&15) + (d>>4); QK^T is
// invariant since Q and K carry the same permutation.
__global__ __launch_bounds__(256, 3) void k_gemm_qkv(const u16* __restrict__ A,
                                                     const u16* __restrict__ Bm,
                                                     u16* __restrict__ qT,
                                                     u16* __restrict__ kT,
                                                     u16* __restrict__ vT,
                                                     const float* __restrict__ tab){
  GEMM_CORE(2048)

  // ---- fused epilogue ----
  const int cb = blockIdx.x*128 + wn*64;   // wave's 64-col span = one head

  if (cb < 2560){
    const bool isq = (cb < 2048);
    const int hh   = (isq ? cb : (cb - 2048)) >> 6;
    const int NH   = isq ? NQ_ : NKV_;
    u16* base      = isq ? qT : kT;
    const float2* t2 = (const float2*)tab;
    #pragma unroll
    for (int i = 0; i < 4; i++){
      const int row0 = blockIdx.y*128 + wm*64 + i*16 + quad*4;
      #pragma unroll
      for (int r = 0; r < 4; r++){
        const int row = row0 + r;
        const int s = row & (S_ - 1), b = row >> 11;
        const float2 c0 = t2[s*32 + l16];
        const float2 c1 = t2[s*32 + 16 + l16];
        const float x10 = acc[i][0][r], x20 = acc[i][2][r];
        const float x11 = acc[i][1][r], x21 = acc[i][3][r];
        const float y10 = x10*c0.x - x20*c0.y;
        const float y20 = x20*c0.x + x10*c0.y;
        const float y11 = x11*c1.x - x21*c1.y;
        const float y21 = x21*c1.x + x11*c1.y;
        uint2 pk;
        asm("v_cvt_pk_bf16_f32 %0, %1, %2" : "=v"(pk.x) : "v"(y10), "v"(y11));
        asm("v_cvt_pk_bf16_f32 %0, %1, %2" : "=v"(pk.y) : "v"(y20), "v"(y21));
        *(uint2*)(base + ((size_t)(b*NH + hh) * S_ + s) * 64 + 4*l16) = pk;
      }
    }
  } else {
    const int fbase = cb - 2560;
    #pragma unroll
    for (int j = 0; j < 4; j++){
      const int f = fbase + j*16 + l16;
      const int kvh = f >> 6, d = f & 63;
      #pragma unroll
      for (int i = 0; i < 4; i++){
        const int row0 = blockIdx.y*128 + wm*64 + i*16 + quad*4;
        const int s0 = row0 & (S_ - 1), b = row0 >> 11;
        uint2 pk;
        pk.x = (unsigned)f2b(acc[i][j][0]) | ((unsigned)f2b(acc[i][j][1]) << 16);
        pk.y = (unsigned)f2b(acc[i][j][2]) | ((unsigned)f2b(acc[i][j][3]) << 16);
        *(uint2*)(vT + ((size_t)(b*NKV_ + kvh) * 64 + d) * S_ + s0) = pk;
      }
    }
  }
}

// ---------------- out-proj GEMM: fp32 epilogue ----------------
__global__ __launch_bounds__(256, 3) void k_gemm_bt(const u16* __restrict__ A,
                                                    const u16* __restrict__ Bm,
                                                    float* __restrict__ C,
                                                    int N){
  GEMM_CORE(2048)
  for (int i = 0; i < 4; i++){
    int row0 = blockIdx.y*128 + wm*64 + i*16 + quad*4;
    for (int j = 0; j < 4; j++){
      int col = blockIdx.x*128 + wn*64 + j*16 + l16;
      for (int r = 0; r < 4; r++)
        C[(size_t)(row0 + r) * N + col] = acc[i][j][r];
    }
  }
}

// ---------------- flash attention: balanced split-K --------------------------
// K is NOT LDS-staged anymore: per (b,kvh) K is 256KB and kvh=bid&7 pins all
// consumers to one XCD -> K+V ~1MB, L2-resident. K fragment reads from L2 are
// exactly as coalesced as the old LDS reads (16 rows x 16B = 16 full lines).
// Dropping Ks halves LDS (32->16KB): residency cap 5 -> 8 blocks/CU.
__constant__ unsigned char JOB_T[40] = {
  15,15,15,15,14,14,11,11,11,10, 7, 7, 3,      // len 8
  14,14,13,13,13,13,12,12,10,10, 9, 9, 6, 6,   // len 7
  12,12, 9, 8, 8, 8, 5, 5, 2,                  // len 6
   4, 4, 1, 0};                                // len 5,5,4,2
__constant__ unsigned char JOB_I[40] = {
   0, 1, 2, 3, 1, 3, 0, 1, 2, 2, 0, 1, 0,
   0, 2, 0, 1, 2, 3, 1, 3, 0, 1, 1, 2, 0, 1,
   0, 2, 0, 0, 1, 2, 0, 1, 0,
   0, 1, 0, 0};
__constant__ unsigned char JOB_C0[40] = {
   0, 8,16,24, 7,22, 0, 8,16,14, 0, 8, 0,
   0,15, 0, 7,14,21, 6,19, 0, 7, 6,13, 0, 7,
   0,13, 0, 0, 6,12, 0, 6, 0,
   0, 5, 0, 0};
__constant__ unsigned char JOB_NC[40] = {
   8, 8, 8, 8, 8, 8, 8, 8, 8, 8, 8, 8, 8,
   7, 7, 7, 7, 7, 7, 7, 7, 7, 7, 7, 7, 7, 7,
   6, 6, 6, 6, 6, 6, 6, 6, 6,
   5, 5, 4, 2};

__global__ __launch_bounds__(256) void k_attn(const u16* __restrict__ qT,
                                              const u16* __restrict__ kT,
                                              const u16* __restrict__ vT,
                                              u16* __restrict__ P1, u16* __restrict__ P2,
                                              u16* __restrict__ P3, u16* __restrict__ P4,
                                              float* __restrict__ l1, float* __restrict__ l2,
                                              float* __restrict__ l3, float* __restrict__ l4){
  __shared__ __align__(16) u16 Vs[2][64*64];

  const int bid  = blockIdx.x;
  const int kvh  = bid & 7;
  const int b    = (bid >> 3) & 1;
  const int hq   = (bid >> 4) & 3;
  const int j    = bid >> 6;            // 0..39 job index, longest first
  const int T    = JOB_T[j];
  const int slot = JOB_I[j];
  const int c0   = JOB_C0[j];
  const int nc   = JOB_NC[j];
  const int h    = kvh*4 + hq;
  const int lane = threadIdx.x & 63, w = threadIdx.x >> 6;
  const int quad = lane >> 4, l16 = lane & 15;

  const u16* Qh = qT + (size_t)(b*NQ_ + h)    * S_ * 64;
  const u16* Kh = kT + (size_t)(b*NKV_ + kvh) * S_ * 64;
  const u16* Vh = vT + (size_t)(b*NKV_ + kvh) * 64 * S_;

  const int rr = lane >> 3;
  const int gg = (lane & 7) ^ rr;
  const int R  = w * 16;

  auto stage = [&](int c, int buf){
    const int kb = c * 64;
    const u16* gv0 = Vh + (size_t)(R + rr)     * S_ + kb + gg*8;
    const u16* gv1 = Vh + (size_t)(R + 8 + rr) * S_ + kb + gg*8;
    __builtin_amdgcn_global_load_lds((const GLB void*)gv0, (LDS void*)&Vs[buf][R*64],     16, 0, 0);
    __builtin_amdgcn_global_load_lds((const GLB void*)gv1, (LDS void*)&Vs[buf][(R+8)*64], 16, 0, 0);
  };

  // V fragment offsets (LDS, swizzled) for the 16x16x32 PV
  const int sw    = l16 & 7;
  const int q2 = quad >> 1, q1 = (quad & 1) * 4;
  const int vo00 = (((q2    ) ^ sw) * 8) + q1;
  const int vo01 = (((q2 + 2) ^ sw) * 8) + q1;
  const int vo10 = (((q2 + 4) ^ sw) * 8) + q1;
  const int vo11 = (((q2 + 6) ^ sw) * 8) + q1;

  const int qb0 = 2*T, qb1 = 2*T + 1;   // diag chunks of strip 0 / strip 1
  const int qr0 = T*128 + w*16 + l16;   // strip 0 query row
  const int qr1 = qr0 + 64;             // strip 1 query row

  stage(c0, 0);

  bf16x8 qf[2][2];
  qf[0][0] = *(const bf16x8*)(Qh + (size_t)qr0*64 + quad*8);
  qf[0][1] = *(const bf16x8*)(Qh + (size_t)qr0*64 + 32 + quad*8);
  qf[1][0] = *(const bf16x8*)(Qh + (size_t)qr1*64 + quad*8);
  qf[1][1] = *(const bf16x8*)(Qh + (size_t)qr1*64 + 32 + quad*8);

  f32x4 o[2][4];
  #pragma unroll
  for (int s = 0; s < 2; s++)
    for (int dt = 0; dt < 4; dt++) o[s][dt] = (f32x4){0.f, 0.f, 0.f, 0.f};
  // l-sums via all-ones-A MFMA (row-sum on the MFMA pipe)
  f32x4 os0 = (f32x4){0.f,0.f,0.f,0.f}, os1 = (f32x4){0.f,0.f,0.f,0.f};
  union { unsigned u[4]; bf16x8 v; } onesu;
  onesu.u[0] = onesu.u[1] = onesu.u[2] = onesu.u[3] = 0x3F803F80u;
  const bf16x8 ones = onesu.v;
  const s16x4 z4 = {0,0,0,0};

  for (int i = 0; i < nc; i++){
    const int c = c0 + i;
    const int buf = i & 1;
    __syncthreads();                      // V-DMA(c) arrived; prev reads done
    if (i + 1 < nc) stage(c + 1, buf^1);

    const int kb = c * 64;
    const bool act0  = (c <= qb0);
    const bool diag0 = (c == qb0);
    const bool diag1 = (c == qb1);
    const u16* Kg = Kh + (size_t)kb * 64;     // K rows direct from L2
    const u16* Vb = &Vs[buf][0];

    s16x4 pk0[4], pk1[4];
    #pragma unroll
    for (int t = 0; t < 4; t++){
      const bool need0 = act0 && !(diag0 && t > w);
      const bool need1 = !(diag1 && t > w);
      if (need0 || need1){
        const u16* kr = Kg + (size_t)(t*16 + l16)*64 + quad*8;
        bf16x8 ka0 = *(const bf16x8*)kr;
        bf16x8 ka1 = *(const bf16x8*)(kr + 32);
        if (need0){
          f32x4 z = (f32x4){0.f, 0.f, 0.f, 0.f};
          z = mfma32(ka0, qf[0][0], z);
          z = mfma32(ka1, qf[0][1], z);
          if (diag0 && t == w){
            #pragma unroll
            for (int r = 0; r < 4; r++)
              if (quad*4 + r > l16) z[r] = -1e30f;   // key > query on the diag
          }
          pk0[t] = exppack(z);
        } else pk0[t] = z4;
        if (need1){
          f32x4 z = (f32x4){0.f, 0.f, 0.f, 0.f};
          z = mfma32(ka0, qf[1][0], z);
          z = mfma32(ka1, qf[1][1], z);
          if (diag1 && t == w){
            #pragma unroll
            for (int r = 0; r < 4; r++)
              if (quad*4 + r > l16) z[r] = -1e30f;
          }
          pk1[t] = exppack(z);
        } else pk1[t] = z4;
      } else { pk0[t] = z4; pk1[t] = z4; }
    }

    bf16x8 pb00 = cat8(pk0[0], pk0[1]), pb01 = cat8(pk0[2], pk0[3]);
    bf16x8 pb10 = cat8(pk1[0], pk1[1]), pb11 = cat8(pk1[2], pk1[3]);

    if (act0){
      os0 = mfma32(ones, pb00, os0);
      os0 = mfma32(ones, pb01, os0);
    }
    os1 = mfma32(ones, pb10, os1);
    os1 = mfma32(ones, pb11, os1);

    #pragma unroll
    for (int dt = 0; dt < 4; dt++){
      const int rowb = (dt*16 + l16)*64;
      bf16x8 va0 = cat8(*(const s16x4*)&Vb[rowb + vo00], *(const s16x4*)&Vb[rowb + vo01]);
      bf16x8 va1 = cat8(*(const s16x4*)&Vb[rowb + vo10], *(const s16x4*)&Vb[rowb + vo11]);
      if (act0){
        o[0][dt] = mfma32(va0, pb00, o[0][dt]);
        o[0][dt] = mfma32(va1, pb01, o[0][dt]);
      }
      o[1][dt] = mfma32(va0, pb10, o[1][dt]);
      o[1][dt] = mfma32(va1, pb11, o[1][dt]);
    }
  }

  // slot-dependent destination (slots 2/3 use compact row layouts)
  u16* Pd; float* ld; int rowoff;
  if      (slot == 0){ Pd = P1; ld = l1; rowoff = b*2048; }
  else if (slot == 1){ Pd = P2; ld = l2; rowoff = b*2048; }
  else if (slot == 2){ Pd = P3; ld = l3; rowoff = b*1024 - 1024; }
  else               { Pd = P4; ld = l4; rowoff = b*512  - 1536; }

  #pragma unroll
  for (int s = 0; s < 2; s++){
    const int qrow = s ? qr1 : qr0;
    const int prow = rowoff + qrow;
    const f32x4 osv = s ? os1 : os0;
    if (quad == 0) ld[(size_t)prow * NQ_ + h] = osv[0];  // full row-sum, no shfl
    u16* orow = Pd + (size_t)prow * D_ + h*64;
    #pragma unroll
    for (int dt = 0; dt < 4; dt++){
      uint2 pkd;
      u16 e0 = f2b(o[s][dt][0]), e1 = f2b(o[s][dt][1]);
      u16 e2 = f2b(o[s][dt][2]), e3 = f2b(o[s][dt][3]);
      pkd.x = (unsigned)e0 | ((unsigned)e1 << 16);
      pkd.y = (unsigned)e2 | ((unsigned)e3 << 16);
      *(uint2*)(orow + dt*16 + quad*4) = pkd;
    }
  }
}

// ---------------- combine: out = (sum Pi)/(sum li), bf16 ----------------
__global__ void k_combine(const u16* __restrict__ P1, const u16* __restrict__ P2,
                          const u16* __restrict__ P3, const u16* __restrict__ P4,
                          const float* __restrict__ l1, const float* __restrict__ l2,
                          const float* __restrict__ l3, const float* __restrict__ l4,
                          u16* __restrict__ out){
  int i = blockIdx.x * blockDim.x + threadIdx.x;   // < 2,097,152
  int e = i << 2;                                  // element index (4 per thread)
  int qrowb = e >> 11;                             // b*2048 + qrow
  int qrow  = qrowb & 2047;
  int b     = qrowb >> 11;
  int h     = (e >> 6) & 31;
  int T     = qrow >> 7;
  int li    = qrowb * NQ_ + h;

  float lsum = l1[li];
  uint2 a = *(const uint2*)(P1 + e);
  float o0 = b2f(a.x & 0xffff), o1 = b2f(a.x >> 16);
  float o2 = b2f(a.y & 0xffff), o3 = b2f(a.y >> 16);
  if (T >= 4){
    lsum += l2[li];
    uint2 p = *(const uint2*)(P2 + e);
    o0 += b2f(p.x & 0xffff); o1 += b2f(p.x >> 16);
    o2 += b2f(p.y & 0xffff); o3 += b2f(p.y >> 16);
  }
  if (T >= 8){
    int r3 = (b << 10) + qrow - 1024;
    lsum += l3[r3 * NQ_ + h];
    uint2 p = *(const uint2*)(P3 + (((size_t)r3) << 11) + (e & 2047));
    o0 += b2f(p.x & 0xffff); o1 += b2f(p.x >> 16);
    o2 += b2f(p.y & 0xffff); o3 += b2f(p.y >> 16);
  }
  if (T >= 12){
    int r4 = (b << 9) + qrow - 1536;
    lsum += l4[r4 * NQ_ + h];
    uint2 p = *(const uint2*)(P4 + (((size_t)r4) << 11) + (e & 2047));
    o0 += b2f(p.x & 0xffff); o1 += b2f(p.x >> 16);
    o2 += b2f(p.y & 0xffff); o3 += b2f(p.y >> 16);
  }
  float inv = 1.0f / lsum;
  uint2 pk;
  pk.x = (unsigned)f2b(o0 * inv) | ((unsigned)f2b(o1 * inv) << 16);
  pk.y = (unsigned)f2b(o2 * inv) | ((unsigned)f2b(o3 * inv) << 16);
  *(uint2*)(out + e) = pk;
}

// ---------------- launcher ----------------
extern "C" void kernel_launch(void* const* d_in, const int* in_sizes, int n_in,
                              void* d_out, int out_size, void* d_ws, size_t ws_size,
                              hipStream_t stream){
  const float* x  = (const float*)d_in[0];
  // d_in[1] = attention_mask (all ones; reference never applies it) -> ignored
  const float* Wq = (const float*)d_in[2];
  const float* Wk = (const float*)d_in[3];
  const float* Wv = (const float*)d_in[4];
  const float* Wo = (const float*)d_in[5];

  char* ws = (char*)d_ws;
  u16*   xb    = (u16*)(ws);               // [0,16M)  x bf16 (dead after gemm_qkv)
  u16*   wqkvb = (u16*)(ws + 16777216);    // [16,28M) QKV weights bf16 (dead after gemm_qkv)
  u16*   wob   = (u16*)(ws + 29360128);    // [28,36M) Wo bf16 (live till gemm_bt)
  u16*   qTp   = (u16*)(ws + 37748736);    // [36,52M) q RoPE'd (dead after attn)
  u16*   kTp   = (u16*)(ws + 54525952);    // [52,56M) k RoPE'd
  u16*   vTp   = (u16*)(ws + 58720256);    // [56,60M) v transposed
  u16*   P1    = xb;                       // [0,16M)  partial slot0 (over dead xb)
  u16*   P2    = (u16*)(ws + 62914560);    // [60,76M) partial slot1
  u16*   P3    = (u16*)(ws + 16777216);    // slot2 compact (over dead wqkvb), 8MB
  u16*   P4    = (u16*)(ws + 25165824);    // slot3 compact, 4MB (ends at wob)
  float* l1    = (float*)(ws + 79691776);  // 512KB
  float* l2    = (float*)(ws + 80216064);  // 512KB
  float* l3    = (float*)d_out;            // scratch until gemm_bt overwrites
  float* l4    = (float*)((char*)d_out + 262144);
  float* ropetab = (float*)(ws + 62914560); // 512KB table over P2 (dead until attn)
  u16*   attnOut = qTp;                    // combine writes over dead qTp

  // all fp32 -> bf16 converts (+QSCALE fold into Wq) + RoPE table, one launch
  k_f2b_all<<<dim3(18496), 256, 0, stream>>>(x, Wq, Wk, Wv, Wo, xb, wqkvb, wob, ropetab);

  // fused QKV projection + RoPE (table) + permuted-d Q/K store + V scatter
  k_gemm_qkv<<<dim3(24, 32), 256, 0, stream>>>(xb, wqkvb, qTp, kTp, vTp, ropetab);

  // balanced split-K flash attention: 2560 jobs of <= 8 chunks, longest-first
  k_attn<<<dim3(2560), 256, 0, stream>>>(qTp, kTp, vTp, P1, P2, P3, P4, l1, l2, l3, l4);

  // combine partials + normalize
  k_combine<<<dim3(8192), 256, 0, stream>>>(P1, P2, P3, P4, l1, l2, l3, l4, attnOut);

  // output projection: (4096 x 2048) * (2048 x 2048)^T -> fp32 d_out
  k_gemm_bt<<<dim3(16, 32), 256, 0, stream>>>(attnOut, wob, (float*)d_out, 2048);
}

// Round 8
// 278.615 us; speedup vs baseline: 1.0812x; 1.0812x over previous
//
#include <hip/hip_runtime.h>

// Problem constants
#define B_   2
#define S_   2048
#define D_   2048
#define NQ_  32
#define NKV_ 8
#define HD_  64
// g = NQ/NKV = 4

#define QSCALE 0.18033688011112042f   // log2(e)/sqrt(HD), folded into Wq at convert

typedef unsigned short u16;
typedef __bf16 bf16x8 __attribute__((ext_vector_type(8)));
typedef short  s16x4  __attribute__((ext_vector_type(4)));
typedef float  f32x4  __attribute__((ext_vector_type(4)));

#define GLB __attribute__((address_space(1)))
#define LDS __attribute__((address_space(3)))

__device__ inline u16 f2b(float f){
  union { float f; unsigned u; } v; v.f = f;
  unsigned r = (v.u + 0x7fffu + ((v.u >> 16) & 1u)) >> 16;
  return (u16)r;
}
__device__ inline float b2f(u16 b){
  union { unsigned u; float f; } v; v.u = ((unsigned)b) << 16;
  return v.f;
}

__device__ inline f32x4 mfma32(bf16x8 a, bf16x8 b, f32x4 c){
  return __builtin_amdgcn_mfma_f32_16x16x32_bf16(a, b, c, 0, 0, 0);
}

// concat two s16x4 (bf16 bit patterns) into one bf16x8 MFMA operand
__device__ inline bf16x8 cat8(s16x4 lo, s16x4 hi){
  union { struct { s16x4 a, b; } s; bf16x8 v; } u;
  u.s.a = lo; u.s.b = hi; return u.v;
}

// exp2 of 4 scores -> RNE-packed bf16 via v_cvt_pk_bf16_f32
__device__ inline s16x4 exppack(f32x4 z){
  float p0 = __builtin_amdgcn_exp2f(z[0]);
  float p1 = __builtin_amdgcn_exp2f(z[1]);
  float p2 = __builtin_amdgcn_exp2f(z[2]);
  float p3 = __builtin_amdgcn_exp2f(z[3]);
  union { uint2 u; s16x4 v; } r;
  asm("v_cvt_pk_bf16_f32 %0, %1, %2" : "=v"(r.u.x) : "v"(p0), "v"(p1));
  asm("v_cvt_pk_bf16_f32 %0, %1, %2" : "=v"(r.u.y) : "v"(p2), "v"(p3));
  return r.v;
}

// ---------- fp32 -> bf16 convert (all 5 regions) + RoPE cos/sin table -------
__global__ void k_f2b_all(const float* __restrict__ x,  const float* __restrict__ wq,
                          const float* __restrict__ wk, const float* __restrict__ wv,
                          const float* __restrict__ wo,
                          u16* __restrict__ xb, u16* __restrict__ wqkvb, u16* __restrict__ wob,
                          float* __restrict__ tab){
  int i = blockIdx.x * blockDim.x + threadIdx.x;   // < 4718592 + 16384
  if (i < 4718592){
    const float* src; u16* dst; int off; float sc = 1.0f;
    if (i < 2097152)      { src = x;  dst = xb;                  off = i; }
    else if (i < 3145728) { src = wq; dst = wqkvb;               off = i - 2097152; sc = QSCALE; }
    else if (i < 3407872) { src = wk; dst = wqkvb + 2048*2048;   off = i - 3145728; }
    else if (i < 3670016) { src = wv; dst = wqkvb + 2560*2048;   off = i - 3407872; }
    else                  { src = wo; dst = wob;                 off = i - 3670016; }
    float4 f = ((const float4*)src)[off];
    uint2 pk;
    pk.x = (unsigned)f2b(f.x*sc) | ((unsigned)f2b(f.y*sc) << 16);
    pk.y = (unsigned)f2b(f.z*sc) | ((unsigned)f2b(f.w*sc) << 16);
    ((uint2*)dst)[off] = pk;
  } else {
    int t = i - 4718592;                // < 16384 : 4 table entries per thread
    float fs = (float)(t >> 3);         // s
    int d2b  = (t & 7) * 4;             // d2 base
    float a0 = fs * __expf(-(float)(d2b    ) * (9.210340371976184f/32.0f));
    float a1 = fs * __expf(-(float)(d2b + 1) * (9.210340371976184f/32.0f));
    float a2 = fs * __expf(-(float)(d2b + 2) * (9.210340371976184f/32.0f));
    float a3 = fs * __expf(-(float)(d2b + 3) * (9.210340371976184f/32.0f));
    float4 o0, o1;
    o0.x = __cosf(a0); o0.y = __sinf(a0); o0.z = __cosf(a1); o0.w = __sinf(a1);
    o1.x = __cosf(a2); o1.y = __sinf(a2); o1.z = __cosf(a3); o1.w = __sinf(a3);
    ((float4*)tab)[2*t]   = o0;
    ((float4*)tab)[2*t+1] = o1;
  }
}

// ======================= shared GEMM core (BK=64, swizzled LDS) =============
// XCD-chunked bijective blockIdx swizzle (nwg % 8 == 0 for both users):
// HW slot lin -> work (lin&7)*(nwg/8) + lin>>3, so each XCD gets a contiguous
// chunk of tiles -> A-panels become XCD-L2-resident.
#define GEMM_CORE(K, GX, GY)                                                   \
  __shared__ __align__(16) u16 As[128*64];                                     \
  __shared__ __align__(16) u16 Bs[128*64];                                     \
  const int tid  = threadIdx.x;                                               \
  const int lane = tid & 63;                                                  \
  const int wave = tid >> 6;                                                  \
  const int wm = wave >> 1, wn = wave & 1;                                    \
  const int quad = lane >> 4, l16 = lane & 15;                                \
  const int lin = blockIdx.y * (GX) + blockIdx.x;                             \
  const int w8  = (lin & 7) * (((GX)*(GY)) >> 3) + (lin >> 3);                \
  const int BX  = w8 % (GX);                                                  \
  const int BY  = w8 / (GX);                                                  \
  const u16* Ab = A  + (size_t)BY * 128 * (K);                                \
  const u16* Bb = Bm + (size_t)BX * 128 * (K);                                \
  f32x4 acc[4][4];                                                            \
  for (int i = 0; i < 4; i++)                                                 \
    for (int j = 0; j < 4; j++) acc[i][j] = (f32x4){0.f, 0.f, 0.f, 0.f};      \
  const int R0 = wave * 32;                                                   \
  const int lr = lane >> 3;                                                   \
  const int gc = ((lane & 7) ^ lr) * 8;                                       \
  const int sk = l16 & 7;                                                     \
  for (int k0 = 0; k0 < (K); k0 += 64){                                       \
    __syncthreads();                                                          \
    _Pragma("unroll")                                                         \
    for (int m = 0; m < 4; m++){                                              \
      const u16* ga = Ab + (size_t)(R0 + m*8 + lr) * (K) + k0 + gc;           \
      const u16* gb = Bb + (size_t)(R0 + m*8 + lr) * (K) + k0 + gc;           \
      __builtin_amdgcn_global_load_lds((const GLB void*)ga, (LDS void*)&As[(R0 + m*8)*64], 16, 0, 0); \
      __builtin_amdgcn_global_load_lds((const GLB void*)gb, (LDS void*)&Bs[(R0 + m*8)*64], 16, 0, 0); \
    }                                                                          \
    __syncthreads();                                                          \
    bf16x8 af[4][2], bfr[4][2];                                               \
    _Pragma("unroll")                                                         \
    for (int i = 0; i < 4; i++)                                               \
      _Pragma("unroll")                                                       \
      for (int h = 0; h < 2; h++)                                             \
        af[i][h]  = *(const bf16x8*)&As[(wm*64 + i*16 + l16)*64 + (((h*4 + quad) ^ sk)*8)]; \
    _Pragma("unroll")                                                         \
    for (int j = 0; j < 4; j++)                                               \
      _Pragma("unroll")                                                       \
      for (int h = 0; h < 2; h++)                                             \
        bfr[j][h] = *(const bf16x8*)&Bs[(wn*64 + j*16 + l16)*64 + (((h*4 + quad) ^ sk)*8)]; \
    _Pragma("unroll")                                                         \
    for (int i = 0; i < 4; i++)                                               \
      _Pragma("unroll")                                                       \
      for (int j = 0; j < 4; j++){                                            \
        acc[i][j] = __builtin_amdgcn_mfma_f32_16x16x32_bf16(af[i][0], bfr[j][0], acc[i][j], 0, 0, 0); \
        acc[i][j] = __builtin_amdgcn_mfma_f32_16x16x32_bf16(af[i][1], bfr[j][1], acc[i][j], 0, 0, 0); \
      }                                                                        \
  }

// ---------------- fused QKV GEMM + RoPE + scatter ----------------
// qT/kT use a PERMUTED head-dim layout: d' = 4*(d&15) + (d>>4); QK^T is
// invariant since Q and K carry the same permutation.
__global__ __launch_bounds__(256, 3) void k_gemm_qkv(const u16* __restrict__ A,
                                                     const u16* __restrict__ Bm,
                                                     u16* __restrict__ qT,
                                                     u16* __restrict__ kT,
                                                     u16* __restrict__ vT,
                                                     const float* __restrict__ tab){
  GEMM_CORE(2048, 24, 32)

  // ---- fused epilogue ----
  const int cb = BX*128 + wn*64;   // wave's 64-col span = one head

  if (cb < 2560){
    const bool isq = (cb < 2048);
    const int hh   = (isq ? cb : (cb - 2048)) >> 6;
    const int NH   = isq ? NQ_ : NKV_;
    u16* base      = isq ? qT : kT;
    const float2* t2 = (const float2*)tab;
    #pragma unroll
    for (int i = 0; i < 4; i++){
      const int row0 = BY*128 + wm*64 + i*16 + quad*4;
      #pragma unroll
      for (int r = 0; r < 4; r++){
        const int row = row0 + r;
        const int s = row & (S_ - 1), b = row >> 11;
        const float2 c0 = t2[s*32 + l16];
        const float2 c1 = t2[s*32 + 16 + l16];
        const float x10 = acc[i][0][r], x20 = acc[i][2][r];
        const float x11 = acc[i][1][r], x21 = acc[i][3][r];
        const float y10 = x10*c0.x - x20*c0.y;
        const float y20 = x20*c0.x + x10*c0.y;
        const float y11 = x11*c1.x - x21*c1.y;
        const float y21 = x21*c1.x + x11*c1.y;
        uint2 pk;
        asm("v_cvt_pk_bf16_f32 %0, %1, %2" : "=v"(pk.x) : "v"(y10), "v"(y11));
        asm("v_cvt_pk_bf16_f32 %0, %1, %2" : "=v"(pk.y) : "v"(y20), "v"(y21));
        *(uint2*)(base + ((size_t)(b*NH + hh) * S_ + s) * 64 + 4*l16) = pk;
      }
    }
  } else {
    const int fbase = cb - 2560;
    #pragma unroll
    for (int j = 0; j < 4; j++){
      const int f = fbase + j*16 + l16;
      const int kvh = f >> 6, d = f & 63;
      #pragma unroll
      for (int i = 0; i < 4; i++){
        const int row0 = BY*128 + wm*64 + i*16 + quad*4;
        const int s0 = row0 & (S_ - 1), b = row0 >> 11;
        uint2 pk;
        pk.x = (unsigned)f2b(acc[i][j][0]) | ((unsigned)f2b(acc[i][j][1]) << 16);
        pk.y = (unsigned)f2b(acc[i][j][2]) | ((unsigned)f2b(acc[i][j][3]) << 16);
        *(uint2*)(vT + ((size_t)(b*NKV_ + kvh) * 64 + d) * S_ + s0) = pk;
      }
    }
  }
}

// ---------------- out-proj GEMM: fp32 epilogue ----------------
__global__ __launch_bounds__(256, 3) void k_gemm_bt(const u16* __restrict__ A,
                                                    const u16* __restrict__ Bm,
                                                    float* __restrict__ C,
                                                    int N){
  GEMM_CORE(2048, 16, 32)
  for (int i = 0; i < 4; i++){
    int row0 = BY*128 + wm*64 + i*16 + quad*4;
    for (int j = 0; j < 4; j++){
      int col = BX*128 + wn*64 + j*16 + l16;
      for (int r = 0; r < 4; r++)
        C[(size_t)(row0 + r) * N + col] = acc[i][j][r];
    }
  }
}

// ---------------- flash attention: balanced split-K --------------------------
// Round-5 structure restored: K AND V double-buffered in LDS via DMA (the
// round-6 de-stage regressed 68->97us: direct L2 K reads put ~200cy latency on
// the barrier->MFMA critical path; LDS was never the occupancy limiter).
// + s_setprio(1) around the MFMA cluster (independent blocks = phase-diverse).
__constant__ unsigned char JOB_T[40] = {
  15,15,15,15,14,14,11,11,11,10, 7, 7, 3,      // len 8
  14,14,13,13,13,13,12,12,10,10, 9, 9, 6, 6,   // len 7
  12,12, 9, 8, 8, 8, 5, 5, 2,                  // len 6
   4, 4, 1, 0};                                // len 5,5,4,2
__constant__ unsigned char JOB_I[40] = {
   0, 1, 2, 3, 1, 3, 0, 1, 2, 2, 0, 1, 0,
   0, 2, 0, 1, 2, 3, 1, 3, 0, 1, 1, 2, 0, 1,
   0, 2, 0, 0, 1, 2, 0, 1, 0,
   0, 1, 0, 0};
__constant__ unsigned char JOB_C0[40] = {
   0, 8,16,24, 7,22, 0, 8,16,14, 0, 8, 0,
   0,15, 0, 7,14,21, 6,19, 0, 7, 6,13, 0, 7,
   0,13, 0, 0, 6,12, 0, 6, 0,
   0, 5, 0, 0};
__constant__ unsigned char JOB_NC[40] = {
   8, 8, 8, 8, 8, 8, 8, 8, 8, 8, 8, 8, 8,
   7, 7, 7, 7, 7, 7, 7, 7, 7, 7, 7, 7, 7, 7,
   6, 6, 6, 6, 6, 6, 6, 6, 6,
   5, 5, 4, 2};

__global__ __launch_bounds__(256) void k_attn(const u16* __restrict__ qT,
                                              const u16* __restrict__ kT,
                                              const u16* __restrict__ vT,
                                              u16* __restrict__ P1, u16* __restrict__ P2,
                                              u16* __restrict__ P3, u16* __restrict__ P4,
                                              float* __restrict__ l1, float* __restrict__ l2,
                                              float* __restrict__ l3, float* __restrict__ l4){
  __shared__ __align__(16) u16 Ks[2][64*64];
  __shared__ __align__(16) u16 Vs[2][64*64];

  const int bid  = blockIdx.x;
  const int kvh  = bid & 7;
  const int b    = (bid >> 3) & 1;
  const int hq   = (bid >> 4) & 3;
  const int j    = bid >> 6;            // 0..39 job index, longest first
  const int T    = JOB_T[j];
  const int slot = JOB_I[j];
  const int c0   = JOB_C0[j];
  const int nc   = JOB_NC[j];
  const int h    = kvh*4 + hq;
  const int lane = threadIdx.x & 63, w = threadIdx.x >> 6;
  const int quad = lane >> 4, l16 = lane & 15;

  const u16* Qh = qT + (size_t)(b*NQ_ + h)    * S_ * 64;
  const u16* Kh = kT + (size_t)(b*NKV_ + kvh) * S_ * 64;
  const u16* Vh = vT + (size_t)(b*NKV_ + kvh) * 64 * S_;

  const int rr = lane >> 3;
  const int gg = (lane & 7) ^ rr;
  const int R  = w * 16;

  auto stage = [&](int c, int buf){
    const int kb = c * 64;
    const u16* gk0 = Kh + (size_t)(kb + R + rr)     * 64 + gg*8;
    const u16* gk1 = Kh + (size_t)(kb + R + 8 + rr) * 64 + gg*8;
    const u16* gv0 = Vh + (size_t)(R + rr)     * S_ + kb + gg*8;
    const u16* gv1 = Vh + (size_t)(R + 8 + rr) * S_ + kb + gg*8;
    __builtin_amdgcn_global_load_lds((const GLB void*)gk0, (LDS void*)&Ks[buf][R*64],     16, 0, 0);
    __builtin_amdgcn_global_load_lds((const GLB void*)gk1, (LDS void*)&Ks[buf][(R+8)*64], 16, 0, 0);
    __builtin_amdgcn_global_load_lds((const GLB void*)gv0, (LDS void*)&Vs[buf][R*64],     16, 0, 0);
    __builtin_amdgcn_global_load_lds((const GLB void*)gv1, (LDS void*)&Vs[buf][(R+8)*64], 16, 0, 0);
  };

  // hoisted chunk-invariant swizzled offsets (u16 units)
  const int sw    = l16 & 7;
  const int koff0 = ((quad    ) ^ sw) * 8;
  const int koff1 = ((quad + 4) ^ sw) * 8;
  // V fragment offsets for the 16x16x32 PV (group tt: lo = tile 2tt, hi = 2tt+1)
  const int q2 = quad >> 1, q1 = (quad & 1) * 4;
  const int vo00 = (((q2    ) ^ sw) * 8) + q1;
  const int vo01 = (((q2 + 2) ^ sw) * 8) + q1;
  const int vo10 = (((q2 + 4) ^ sw) * 8) + q1;
  const int vo11 = (((q2 + 6) ^ sw) * 8) + q1;

  const int qb0 = 2*T, qb1 = 2*T + 1;   // diag chunks of strip 0 / strip 1
  const int qr0 = T*128 + w*16 + l16;   // strip 0 query row
  const int qr1 = qr0 + 64;             // strip 1 query row

  stage(c0, 0);

  bf16x8 qf[2][2];
  qf[0][0] = *(const bf16x8*)(Qh + (size_t)qr0*64 + quad*8);
  qf[0][1] = *(const bf16x8*)(Qh + (size_t)qr0*64 + 32 + quad*8);
  qf[1][0] = *(const bf16x8*)(Qh + (size_t)qr1*64 + quad*8);
  qf[1][1] = *(const bf16x8*)(Qh + (size_t)qr1*64 + 32 + quad*8);

  f32x4 o[2][4];
  #pragma unroll
  for (int s = 0; s < 2; s++)
    for (int dt = 0; dt < 4; dt++) o[s][dt] = (f32x4){0.f, 0.f, 0.f, 0.f};
  // l-sums via all-ones-A MFMA (row-sum on the MFMA pipe)
  f32x4 os0 = (f32x4){0.f,0.f,0.f,0.f}, os1 = (f32x4){0.f,0.f,0.f,0.f};
  union { unsigned u[4]; bf16x8 v; } onesu;
  onesu.u[0] = onesu.u[1] = onesu.u[2] = onesu.u[3] = 0x3F803F80u;
  const bf16x8 ones = onesu.v;
  const s16x4 z4 = {0,0,0,0};

  for (int i = 0; i < nc; i++){
    const int c = c0 + i;
    const int buf = i & 1;
    __syncthreads();                      // DMA(c) arrived; prev reads done
    if (i + 1 < nc) stage(c + 1, buf^1);

    const bool act0  = (c <= qb0);
    const bool diag0 = (c == qb0);
    const bool diag1 = (c == qb1);
    const u16* Kb = &Ks[buf][0];
    const u16* Vb = &Vs[buf][0];

    s16x4 pk0[4], pk1[4];
    #pragma unroll
    for (int t = 0; t < 4; t++){
      const bool need0 = act0 && !(diag0 && t > w);
      const bool need1 = !(diag1 && t > w);
      if (need0 || need1){
        const int rowb = (t*16 + l16)*64;
        bf16x8 ka0 = *(const bf16x8*)&Kb[rowb + koff0];
        bf16x8 ka1 = *(const bf16x8*)&Kb[rowb + koff1];
        if (need0){
          f32x4 z = (f32x4){0.f, 0.f, 0.f, 0.f};
          z = mfma32(ka0, qf[0][0], z);
          z = mfma32(ka1, qf[0][1], z);
          if (diag0 && t == w){
            #pragma unroll
            for (int r = 0; r < 4; r++)
              if (quad*4 + r > l16) z[r] = -1e30f;   // key > query on the diag
          }
          pk0[t] = exppack(z);
        } else pk0[t] = z4;
        if (need1){
          f32x4 z = (f32x4){0.f, 0.f, 0.f, 0.f};
          z = mfma32(ka0, qf[1][0], z);
          z = mfma32(ka1, qf[1][1], z);
          if (diag1 && t == w){
            #pragma unroll
            for (int r = 0; r < 4; r++)
              if (quad*4 + r > l16) z[r] = -1e30f;
          }
          pk1[t] = exppack(z);
        } else pk1[t] = z4;
      } else { pk0[t] = z4; pk1[t] = z4; }
    }

    bf16x8 pb00 = cat8(pk0[0], pk0[1]), pb01 = cat8(pk0[2], pk0[3]);
    bf16x8 pb10 = cat8(pk1[0], pk1[1]), pb11 = cat8(pk1[2], pk1[3]);

    __builtin_amdgcn_s_setprio(1);        // favor the MFMA cluster
    if (act0){
      os0 = mfma32(ones, pb00, os0);
      os0 = mfma32(ones, pb01, os0);
    }
    os1 = mfma32(ones, pb10, os1);
    os1 = mfma32(ones, pb11, os1);

    #pragma unroll
    for (int dt = 0; dt < 4; dt++){
      const int rowb = (dt*16 + l16)*64;
      bf16x8 va0 = cat8(*(const s16x4*)&Vb[rowb + vo00], *(const s16x4*)&Vb[rowb + vo01]);
      bf16x8 va1 = cat8(*(const s16x4*)&Vb[rowb + vo10], *(const s16x4*)&Vb[rowb + vo11]);
      if (act0){
        o[0][dt] = mfma32(va0, pb00, o[0][dt]);
        o[0][dt] = mfma32(va1, pb01, o[0][dt]);
      }
      o[1][dt] = mfma32(va0, pb10, o[1][dt]);
      o[1][dt] = mfma32(va1, pb11, o[1][dt]);
    }
    __builtin_amdgcn_s_setprio(0);
  }

  // slot-dependent destination (slots 2/3 use compact row layouts)
  u16* Pd; float* ld; int rowoff;
  if      (slot == 0){ Pd = P1; ld = l1; rowoff = b*2048; }
  else if (slot == 1){ Pd = P2; ld = l2; rowoff = b*2048; }
  else if (slot == 2){ Pd = P3; ld = l3; rowoff = b*1024 - 1024; }
  else               { Pd = P4; ld = l4; rowoff = b*512  - 1536; }

  #pragma unroll
  for (int s = 0; s < 2; s++){
    const int qrow = s ? qr1 : qr0;
    const int prow = rowoff + qrow;
    const f32x4 osv = s ? os1 : os0;
    if (quad == 0) ld[(size_t)prow * NQ_ + h] = osv[0];  // full row-sum, no shfl
    u16* orow = Pd + (size_t)prow * D_ + h*64;
    #pragma unroll
    for (int dt = 0; dt < 4; dt++){
      uint2 pkd;
      u16 e0 = f2b(o[s][dt][0]), e1 = f2b(o[s][dt][1]);
      u16 e2 = f2b(o[s][dt][2]), e3 = f2b(o[s][dt][3]);
      pkd.x = (unsigned)e0 | ((unsigned)e1 << 16);
      pkd.y = (unsigned)e2 | ((unsigned)e3 << 16);
      *(uint2*)(orow + dt*16 + quad*4) = pkd;
    }
  }
}

// ---------------- combine: out = (sum Pi)/(sum li), bf16 ----------------
__global__ void k_combine(const u16* __restrict__ P1, const u16* __restrict__ P2,
                          const u16* __restrict__ P3, const u16* __restrict__ P4,
                          const float* __restrict__ l1, const float* __restrict__ l2,
                          const float* __restrict__ l3, const float* __restrict__ l4,
                          u16* __restrict__ out){
  int i = blockIdx.x * blockDim.x + threadIdx.x;   // < 2,097,152
  int e = i << 2;                                  // element index (4 per thread)
  int qrowb = e >> 11;                             // b*2048 + qrow
  int qrow  = qrowb & 2047;
  int b     = qrowb >> 11;
  int h     = (e >> 6) & 31;
  int T     = qrow >> 7;
  int li    = qrowb * NQ_ + h;

  float lsum = l1[li];
  uint2 a = *(const uint2*)(P1 + e);
  float o0 = b2f(a.x & 0xffff), o1 = b2f(a.x >> 16);
  float o2 = b2f(a.y & 0xffff), o3 = b2f(a.y >> 16);
  if (T >= 4){
    lsum += l2[li];
    uint2 p = *(const uint2*)(P2 + e);
    o0 += b2f(p.x & 0xffff); o1 += b2f(p.x >> 16);
    o2 += b2f(p.y & 0xffff); o3 += b2f(p.y >> 16);
  }
  if (T >= 8){
    int r3 = (b << 10) + qrow - 1024;
    lsum += l3[r3 * NQ_ + h];
    uint2 p = *(const uint2*)(P3 + (((size_t)r3) << 11) + (e & 2047));
    o0 += b2f(p.x & 0xffff); o1 += b2f(p.x >> 16);
    o2 += b2f(p.y & 0xffff); o3 += b2f(p.y >> 16);
  }
  if (T >= 12){
    int r4 = (b << 9) + qrow - 1536;
    lsum += l4[r4 * NQ_ + h];
    uint2 p = *(const uint2*)(P4 + (((size_t)r4) << 11) + (e & 2047));
    o0 += b2f(p.x & 0xffff); o1 += b2f(p.x >> 16);
    o2 += b2f(p.y & 0xffff); o3 += b2f(p.y >> 16);
  }
  float inv = 1.0f / lsum;
  uint2 pk;
  pk.x = (unsigned)f2b(o0 * inv) | ((unsigned)f2b(o1 * inv) << 16);
  pk.y = (unsigned)f2b(o2 * inv) | ((unsigned)f2b(o3 * inv) << 16);
  *(uint2*)(out + e) = pk;
}

// ---------------- launcher ----------------
extern "C" void kernel_launch(void* const* d_in, const int* in_sizes, int n_in,
                              void* d_out, int out_size, void* d_ws, size_t ws_size,
                              hipStream_t stream){
  const float* x  = (const float*)d_in[0];
  // d_in[1] = attention_mask (all ones; reference never applies it) -> ignored
  const float* Wq = (const float*)d_in[2];
  const float* Wk = (const float*)d_in[3];
  const float* Wv = (const float*)d_in[4];
  const float* Wo = (const float*)d_in[5];

  char* ws = (char*)d_ws;
  u16*   xb    = (u16*)(ws);               // [0,16M)  x bf16 (dead after gemm_qkv)
  u16*   wqkvb = (u16*)(ws + 16777216);    // [16,28M) QKV weights bf16 (dead after gemm_qkv)
  u16*   wob   = (u16*)(ws + 29360128);    // [28,36M) Wo bf16 (live till gemm_bt)
  u16*   qTp   = (u16*)(ws + 37748736);    // [36,52M) q RoPE'd (dead after attn)
  u16*   kTp   = (u16*)(ws + 54525952);    // [52,56M) k RoPE'd
  u16*   vTp   = (u16*)(ws + 58720256);    // [56,60M) v transposed
  u16*   P1    = xb;                       // [0,16M)  partial slot0 (over dead xb)
  u16*   P2    = (u16*)(ws + 62914560);    // [60,76M) partial slot1
  u16*   P3    = (u16*)(ws + 16777216);    // slot2 compact (over dead wqkvb), 8MB
  u16*   P4    = (u16*)(ws + 25165824);    // slot3 compact, 4MB (ends at wob)
  float* l1    = (float*)(ws + 79691776);  // 512KB
  float* l2    = (float*)(ws + 80216064);  // 512KB
  float* l3    = (float*)d_out;            // scratch until gemm_bt overwrites
  float* l4    = (float*)((char*)d_out + 262144);
  float* ropetab = (float*)(ws + 62914560); // 512KB table over P2 (dead until attn)
  u16*   attnOut = qTp;                    // combine writes over dead qTp

  // all fp32 -> bf16 converts (+QSCALE fold into Wq) + RoPE table, one launch
  k_f2b_all<<<dim3(18496), 256, 0, stream>>>(x, Wq, Wk, Wv, Wo, xb, wqkvb, wob, ropetab);

  // fused QKV projection + RoPE (table) + permuted-d Q/K store + V scatter
  k_gemm_qkv<<<dim3(24, 32), 256, 0, stream>>>(xb, wqkvb, qTp, kTp, vTp, ropetab);

  // balanced split-K flash attention: 2560 jobs of <= 8 chunks, longest-first
  k_attn<<<dim3(2560), 256, 0, stream>>>(qTp, kTp, vTp, P1, P2, P3, P4, l1, l2, l3, l4);

  // combine partials + normalize
  k_combine<<<dim3(8192), 256, 0, stream>>>(P1, P2, P3, P4, l1, l2, l3, l4, attnOut);

  // output projection: (4096 x 2048) * (2048 x 2048)^T -> fp32 d_out
  k_gemm_bt<<<dim3(16, 32), 256, 0, stream>>>(attnOut, wob, (float*)d_out, 2048);
}